// Round 8
// baseline (465539.209 us; speedup 1.0000x reference)
//
#include <hip/hip_runtime.h>

#define T_STEPS 32768
#define THREADS 256
#define NLAUNCH 512   // WGs launched; 64 become workers, rest exit
#define D_SLOTS 4     // h rotation depth (max producer skew = 1)

typedef unsigned int uint32;
typedef unsigned long long ull;
typedef unsigned int u32x4 __attribute__((ext_vector_type(4)));

// ws layout:
// [0, 32768)       : hrot = ull[2 lstm][D_SLOTS][512]; each ull = {lo: tag=t+1, hi: f32 h}
// [32768, 32896)   : claim area (32 uints)

__device__ inline float fsig(float x) {
    return __builtin_amdgcn_rcpf(1.f + __expf(-x));
}
__device__ inline float ftanh(float x) {
    return 1.f - 2.f * __builtin_amdgcn_rcpf(1.f + __expf(2.f * x));
}

// L1-bypassing local-L2 read: invalidate vector L1, then plain load (which
// must now miss L1 and be served by the XCD-local L2 -- the same cache the
// producers' plain write-through stores land in). No RMW -> no memory-side trip.
__device__ inline void poll16(const ull* p, u32x4& v) {
    asm volatile("buffer_inv\n\t"
                 "s_waitcnt vmcnt(0)\n\t"
                 "global_load_dwordx4 %0, %1, off\n\t"
                 "s_waitcnt vmcnt(0)"
                 : "=v"(v) : "v"(p) : "memory");
}

// claim-phase primitives (agent scope; startup-only) + rescue RMW (memory-side,
// slow but round-7-proven fresh)
__device__ inline uint32 a_add(uint32* p, uint32 v) {
    return __hip_atomic_fetch_add(p, v, __ATOMIC_RELAXED, __HIP_MEMORY_SCOPE_AGENT);
}
__device__ inline uint32 a_ld(const uint32* p) {
    return __hip_atomic_load(p, __ATOMIC_RELAXED, __HIP_MEMORY_SCOPE_AGENT);
}
__device__ inline void a_st(uint32* p, uint32 v) {
    __hip_atomic_store(p, v, __ATOMIC_RELAXED, __HIP_MEMORY_SCOPE_AGENT);
}
__device__ inline ull rescue_rmw(ull* p) {
    return __hip_atomic_fetch_add(p, 0ull, __ATOMIC_RELAXED, __HIP_MEMORY_SCOPE_AGENT);
}

__global__ __launch_bounds__(THREADS, 2)
void lstm_persistent(const float* __restrict__ sa,
                     const float* __restrict__ W_ih1, const float* __restrict__ W_hh1,
                     const float* __restrict__ b_ih1, const float* __restrict__ b_hh1,
                     const float* __restrict__ W_ih2, const float* __restrict__ W_hh2,
                     const float* __restrict__ b_ih2, const float* __restrict__ b_hh2,
                     const float* __restrict__ W_xyz, const float* __restrict__ W_zeta,
                     const float* __restrict__ W_uvw, const float* __restrict__ W_pqr,
                     float* __restrict__ out, ull* hrot, uint32* claim)
{
    const int tid  = threadIdx.x;
    const int wave = tid >> 6;
    const int lane = tid & 63;

    __shared__ int s_lstm, s_w;

    // ---- XCD-local role claiming (thread 0); agent-scope, startup-only ----
    if (tid == 0) {
        uint32 xcc;
        asm volatile("s_getreg_b32 %0, hwreg(HW_REG_XCC_ID)" : "=s"(xcc));
        xcc &= 7;
        uint32* cnt     = claim;            // [0..7]
        uint32* rankcnt = claim + 8;
        uint32* grank   = claim + 16;       // [xcd*2 + g]

        int lstm = -1, w = 0;
        uint32 slot = a_add(&cnt[xcc], 1);
        if (slot < 64) {
            uint32 g = slot >> 5, role = slot & 31;
            uint32* gr = &grank[xcc * 2 + g];
            if (role == 31) {                 // completer: group is full
                uint32 rank = a_add(rankcnt, 1);
                uint32 val  = (rank < 2) ? (rank + 1) : 0xFEu;
                a_st(gr, val);
                if (val != 0xFEu) { lstm = (int)rank; w = 31; }
            } else {                          // spinner
                for (;;) {
                    uint32 v = a_ld(gr);
                    if (v != 0) {
                        if (v != 0xFEu) { lstm = (int)v - 1; w = (int)role; }
                        break;
                    }
                    if (a_ld(rankcnt) >= 2 && a_ld(&cnt[xcc]) < (g + 1) * 32)
                        break;                // group can never get a valid rank
                }
            }
        }
        s_lstm = lstm; s_w = w;
    }
    __syncthreads();
    const int lstm = s_lstm;
    const int w    = s_w;
    if (lstm < 0) return;

    const float* W_ih = lstm ? W_ih2 : W_ih1;
    const float* W_hh = lstm ? W_hh2 : W_hh1;
    const float* b_ih = lstm ? b_ih2 : b_ih1;
    const float* b_hh = lstm ? b_hh2 : b_hh1;
    const float* W_a  = lstm ? W_zeta : W_xyz;
    const float* W_b  = lstm ? W_pqr  : W_uvw;

    ull* hb = hrot + (size_t)lstm * D_SLOTS * 512;

    __shared__ __align__(16) float h_lds[512];
    __shared__ float part_lds[64 * 5];
    __shared__ float wih_lds[64 * 19];

    const int r    = lane;
    const int jloc = r & 15;
    const int grow = ((r >> 4) << 9) + (w << 4) + jloc;

    // W_hh slice: 128 weights / thread, held in AGPRs (explicit accvgpr ops;
    // register-class constraints make L2/scratch re-streaming impossible).
    float wa[128];
    {
        const float4* wp4 = (const float4*)(W_hh + (size_t)grow * 512 + wave * 128);
        #pragma unroll
        for (int k = 0; k < 32; ++k) {
            float4 t4 = wp4[k];
            asm volatile("v_accvgpr_write_b32 %0, %1" : "=a"(wa[4 * k + 0]) : "v"(t4.x));
            asm volatile("v_accvgpr_write_b32 %0, %1" : "=a"(wa[4 * k + 1]) : "v"(t4.y));
            asm volatile("v_accvgpr_write_b32 %0, %1" : "=a"(wa[4 * k + 2]) : "v"(t4.z));
            asm volatile("v_accvgpr_write_b32 %0, %1" : "=a"(wa[4 * k + 3]) : "v"(t4.w));
        }
    }
    for (int idx = tid; idx < 64 * 19; idx += THREADS) {
        int rr = idx / 19, kk = idx - rr * 19;
        int gr2 = ((rr >> 4) << 9) + (w << 4) + (rr & 15);
        wih_lds[idx] = W_ih[gr2 * 19 + kk];
    }
    const float bsum = b_ih[grow] + b_hh[grow];

    float pj[6];
    #pragma unroll
    for (int o = 0; o < 6; ++o) pj[o] = 0.f;
    if (wave == 1 && lane < 16) {
        #pragma unroll
        for (int o = 0; o < 3; ++o) {
            pj[o]     = W_a[o * 512 + (w << 4) + lane];
            pj[o + 3] = W_b[o * 512 + (w << 4) + lane];
        }
    }

    float c_reg = 0.0f;
    int   thr   = 64;            // spins before memory-side rescue (self-lowering)
    __syncthreads();

    float sav = (wave == 0 && lane < 19) ? sa[lane] : 0.f;

    for (int t = 0; t < T_STEPS; ++t) {
        // ---- 0. gx on the fly (independent of h) ----
        float gxv = bsum;
        if (wave == 0) {
            #pragma unroll
            for (int k = 0; k < 19; ++k)
                gxv = fmaf(__shfl(sav, k), wih_lds[r * 19 + k], gxv);
        }
        float sav_n = 0.f;
        if (wave == 0 && lane < 19 && t + 1 < T_STEPS)
            sav_n = sa[(size_t)(t + 1) * 19 + lane];

        // ---- 1. poll-and-gather h_{t-1}: L1-inv + plain load (local L2) ----
        if (t > 0) {
            ull* sp = hb + (size_t)((uint32)(t - 1) & (D_SLOTS - 1)) * 512 + 2 * tid;
            const uint32 tag = (uint32)t;
            u32x4 v;
            int spin = 0;
            for (;;) {
                poll16(sp, v);
                if (v.x == tag && v.z == tag) break;
                if (++spin >= thr) {             // memory-side rescue (proven path)
                    ull a = rescue_rmw(sp);
                    ull b = rescue_rmw(sp + 1);
                    if ((uint32)a == tag && (uint32)b == tag) {
                        v.x = (uint32)a; v.y = (uint32)(a >> 32);
                        v.z = (uint32)b; v.w = (uint32)(b >> 32);
                        break;
                    }
                    thr = 2;                      // fast path seems broken; adapt
                    spin = 0;
                }
            }
            *(float2*)&h_lds[2 * tid] =
                make_float2(__uint_as_float(v.y), __uint_as_float(v.w));
        } else {
            *(float2*)&h_lds[2 * tid] = make_float2(0.f, 0.f);
        }
        __syncthreads();

        float hprev = 0.f;
        if (wave == 1 && lane < 16) hprev = h_lds[(w << 4) + lane];

        // ---- 2. mat-vec partial: row r, cols [wave*128, wave*128+128) ----
        {
            const float4* hp4 = (const float4*)(h_lds + wave * 128);
            float ax = 0.f, ay = 0.f, az = 0.f, aw = 0.f;
            #pragma unroll
            for (int k = 0; k < 32; ++k) {
                float4 hv = hp4[k];
                float w0, w1, w2, w3;
                asm volatile("v_accvgpr_read_b32 %0, %1" : "=v"(w0) : "a"(wa[4 * k + 0]));
                asm volatile("v_accvgpr_read_b32 %0, %1" : "=v"(w1) : "a"(wa[4 * k + 1]));
                asm volatile("v_accvgpr_read_b32 %0, %1" : "=v"(w2) : "a"(wa[4 * k + 2]));
                asm volatile("v_accvgpr_read_b32 %0, %1" : "=v"(w3) : "a"(wa[4 * k + 3]));
                ax = fmaf(w0, hv.x, ax);
                ay = fmaf(w1, hv.y, ay);
                az = fmaf(w2, hv.z, az);
                aw = fmaf(w3, hv.w, aw);
            }
            part_lds[r * 5 + wave] = (ax + ay) + (az + aw);
        }
        __syncthreads();

        // ---- 3. gate assembly + cell update + publish (wave 0) ----
        if (wave == 0) {
            float pre = part_lds[r * 5] + part_lds[r * 5 + 1] +
                        part_lds[r * 5 + 2] + part_lds[r * 5 + 3] + gxv;

            const int g = r >> 4;
            float act = (g == 2) ? ftanh(pre) : fsig(pre);

            float i_v = __shfl(act, jloc);
            float f_v = __shfl(act, 16 + jloc);
            float g_v = __shfl(act, 32 + jloc);
            float o_v = __shfl(act, 48 + jloc);

            if (r < 16) {
                c_reg = f_v * c_reg + i_v * g_v;
                float hn = o_v * ftanh(c_reg);
                ull pk = ((ull)__float_as_uint(hn) << 32) | (ull)(uint32)(t + 1);
                // plain write-through store into the local XCD L2; fused tag IS the flag
                __hip_atomic_store(
                    &hb[(size_t)((uint32)t & (D_SLOTS - 1)) * 512 + (w << 4) + jloc],
                    pk, __ATOMIC_RELAXED, __HIP_MEMORY_SCOPE_WORKGROUP);
            }
        }
        // ---- 4. deferred output projection for out[t-1] (wave 1) ----
        else if (wave == 1 && lane < 16 && t > 0) {
            #pragma unroll
            for (int o = 0; o < 6; ++o) {
                float v = hprev * pj[o];
                v += __shfl_xor(v, 1);
                v += __shfl_xor(v, 2);
                v += __shfl_xor(v, 4);
                v += __shfl_xor(v, 8);
                if (lane == 0) {
                    int col = (o < 3) ? (3 * lstm + o) : (6 + 3 * lstm + (o - 3));
                    atomicAdd(&out[(size_t)(t - 1) * 12 + col], v);
                }
            }
        }
        sav = sav_n;
    }

    // ---- final projection for out[T-1] (same-CU producer; inv+load spin) ----
    if (wave == 1 && lane < 16) {
        ull* src = hb + (size_t)((uint32)(T_STEPS - 1) & (D_SLOTS - 1)) * 512
                      + (w << 4) + lane;
        const uint32 tag = (uint32)T_STEPS;
        ull a;
        int spin = 0;
        for (;;) {
            u32x4 v;
            poll16(src, v);   // reads 16B; we use the first 8
            a = ((ull)v.y << 32) | v.x;
            if ((uint32)a == tag) break;
            if (++spin >= 64) {
                a = rescue_rmw(src);
                if ((uint32)a == tag) break;
                spin = 0;
            }
        }
        float hl = __uint_as_float((uint32)(a >> 32));
        #pragma unroll
        for (int o = 0; o < 6; ++o) {
            float s = hl * pj[o];
            s += __shfl_xor(s, 1);
            s += __shfl_xor(s, 2);
            s += __shfl_xor(s, 4);
            s += __shfl_xor(s, 8);
            if (lane == 0) {
                int col = (o < 3) ? (3 * lstm + o) : (6 + 3 * lstm + (o - 3));
                atomicAdd(&out[(size_t)(T_STEPS - 1) * 12 + col], s);
            }
        }
    }
}

__global__ void init_out(const float* __restrict__ b_xyz, const float* __restrict__ b_zeta,
                         const float* __restrict__ b_uvw, const float* __restrict__ b_pqr,
                         float* __restrict__ out)
{
    int idx = blockIdx.x * blockDim.x + threadIdx.x;
    if (idx < T_STEPS * 12) {
        int o = idx % 12;
        float v;
        if (o < 3)      v = b_xyz[o];
        else if (o < 6) v = b_zeta[o - 3];
        else if (o < 9) v = b_uvw[o - 6];
        else            v = b_pqr[o - 9];
        out[idx] = v;
    }
}

extern "C" void kernel_launch(void* const* d_in, const int* in_sizes, int n_in,
                              void* d_out, int out_size, void* d_ws, size_t ws_size,
                              hipStream_t stream)
{
    const float* sa    = (const float*)d_in[0];
    const float* W_ih1 = (const float*)d_in[1];
    const float* W_hh1 = (const float*)d_in[2];
    const float* b_ih1 = (const float*)d_in[3];
    const float* b_hh1 = (const float*)d_in[4];
    const float* W_ih2 = (const float*)d_in[5];
    const float* W_hh2 = (const float*)d_in[6];
    const float* b_ih2 = (const float*)d_in[7];
    const float* b_hh2 = (const float*)d_in[8];
    const float* W_xyz = (const float*)d_in[9];
    const float* b_xyz = (const float*)d_in[10];
    const float* W_zeta= (const float*)d_in[11];
    const float* b_zeta= (const float*)d_in[12];
    const float* W_uvw = (const float*)d_in[13];
    const float* b_uvw = (const float*)d_in[14];
    const float* W_pqr = (const float*)d_in[15];
    const float* b_pqr = (const float*)d_in[16];

    float*  out   = (float*)d_out;
    ull*    hrot  = (ull*)d_ws;
    uint32* claim = (uint32*)((char*)d_ws + 2 * D_SLOTS * 512 * sizeof(ull));

    // zero hrot tags + claim area every call (graph-replayed)
    hipMemsetAsync(d_ws, 0, 2 * D_SLOTS * 512 * sizeof(ull) + 128, stream);
    init_out<<<(T_STEPS * 12 + 255) / 256, 256, 0, stream>>>(b_xyz, b_zeta, b_uvw, b_pqr, out);

    lstm_persistent<<<NLAUNCH, THREADS, 0, stream>>>(
        sa, W_ih1, W_hh1, b_ih1, b_hh1, W_ih2, W_hh2, b_ih2, b_hh2,
        W_xyz, W_zeta, W_uvw, W_pqr, out, hrot, claim);
}

// Round 9
// 113517.615 us; speedup vs baseline: 4.1010x; 4.1010x over previous
//
#include <hip/hip_runtime.h>

#define T_STEPS 32768
#define THREADS 256
#define NLAUNCH 512   // WGs launched; 64 become workers, rest exit
#define D_SLOTS 4     // h rotation depth (max producer skew = 1)

typedef unsigned int uint32;
typedef unsigned long long ull;
typedef unsigned int u32x4 __attribute__((ext_vector_type(4)));

// ws layout:
// [0, 32768)       : hrot = ull[2 lstm][D_SLOTS][512]; each ull = {lo: tag=t+1, hi: f32 h}
// [32768, 32896)   : claim area (32 uints)

__device__ inline float fsig(float x) {
    return __builtin_amdgcn_rcpf(1.f + __expf(-x));
}
__device__ inline float ftanh(float x) {
    return 1.f - 2.f * __builtin_amdgcn_rcpf(1.f + __expf(2.f * x));
}

// Non-temporal poll load: nt = no-allocate in L1, so hbuf lines are NEVER
// resident in L1 (no other access path allocates them either) -> every poll
// is served by the XCD-local L2, which the producer's write-through store
// updated. sc0 additionally requests L1 bypass. No RMW -> no memory-side trip.
__device__ inline void poll16(const ull* p, u32x4& v) {
    asm volatile("global_load_dwordx4 %0, %1, off sc0 nt\n\t"
                 "s_waitcnt vmcnt(0)"
                 : "=v"(v) : "v"(p) : "memory");
}

// claim-phase primitives (agent scope; startup-only) + rescue RMW (memory-side,
// slow but round-7-proven fresh)
__device__ inline uint32 a_add(uint32* p, uint32 v) {
    return __hip_atomic_fetch_add(p, v, __ATOMIC_RELAXED, __HIP_MEMORY_SCOPE_AGENT);
}
__device__ inline uint32 a_ld(const uint32* p) {
    return __hip_atomic_load(p, __ATOMIC_RELAXED, __HIP_MEMORY_SCOPE_AGENT);
}
__device__ inline void a_st(uint32* p, uint32 v) {
    __hip_atomic_store(p, v, __ATOMIC_RELAXED, __HIP_MEMORY_SCOPE_AGENT);
}
__device__ inline ull rescue_rmw(ull* p) {
    return __hip_atomic_fetch_add(p, 0ull, __ATOMIC_RELAXED, __HIP_MEMORY_SCOPE_AGENT);
}

__global__ __launch_bounds__(THREADS, 2)
void lstm_persistent(const float* __restrict__ sa,
                     const float* __restrict__ W_ih1, const float* __restrict__ W_hh1,
                     const float* __restrict__ b_ih1, const float* __restrict__ b_hh1,
                     const float* __restrict__ W_ih2, const float* __restrict__ W_hh2,
                     const float* __restrict__ b_ih2, const float* __restrict__ b_hh2,
                     const float* __restrict__ W_xyz, const float* __restrict__ W_zeta,
                     const float* __restrict__ W_uvw, const float* __restrict__ W_pqr,
                     float* __restrict__ out, ull* hrot, uint32* claim)
{
    const int tid  = threadIdx.x;
    const int wave = tid >> 6;
    const int lane = tid & 63;

    __shared__ int s_lstm, s_w;

    // ---- XCD-local role claiming (thread 0); agent-scope, startup-only ----
    if (tid == 0) {
        uint32 xcc;
        asm volatile("s_getreg_b32 %0, hwreg(HW_REG_XCC_ID)" : "=s"(xcc));
        xcc &= 7;
        uint32* cnt     = claim;            // [0..7]
        uint32* rankcnt = claim + 8;
        uint32* grank   = claim + 16;       // [xcd*2 + g]

        int lstm = -1, w = 0;
        uint32 slot = a_add(&cnt[xcc], 1);
        if (slot < 64) {
            uint32 g = slot >> 5, role = slot & 31;
            uint32* gr = &grank[xcc * 2 + g];
            if (role == 31) {                 // completer: group is full
                uint32 rank = a_add(rankcnt, 1);
                uint32 val  = (rank < 2) ? (rank + 1) : 0xFEu;
                a_st(gr, val);
                if (val != 0xFEu) { lstm = (int)rank; w = 31; }
            } else {                          // spinner
                for (;;) {
                    uint32 v = a_ld(gr);
                    if (v != 0) {
                        if (v != 0xFEu) { lstm = (int)v - 1; w = (int)role; }
                        break;
                    }
                    if (a_ld(rankcnt) >= 2 && a_ld(&cnt[xcc]) < (g + 1) * 32)
                        break;                // group can never get a valid rank
                }
            }
        }
        s_lstm = lstm; s_w = w;
    }
    __syncthreads();
    const int lstm = s_lstm;
    const int w    = s_w;
    if (lstm < 0) return;

    const float* W_ih = lstm ? W_ih2 : W_ih1;
    const float* W_hh = lstm ? W_hh2 : W_hh1;
    const float* b_ih = lstm ? b_ih2 : b_ih1;
    const float* b_hh = lstm ? b_hh2 : b_hh1;
    const float* W_a  = lstm ? W_zeta : W_xyz;
    const float* W_b  = lstm ? W_pqr  : W_uvw;

    ull* hb = hrot + (size_t)lstm * D_SLOTS * 512;

    __shared__ __align__(16) float h_lds[512];
    __shared__ float part_lds[64 * 5];
    __shared__ float wih_lds[64 * 19];

    const int r    = lane;
    const int jloc = r & 15;
    const int grow = ((r >> 4) << 9) + (w << 4) + jloc;

    // W_hh slice: 128 weights / thread, held in AGPRs (explicit accvgpr ops;
    // register-class constraints make L2/scratch re-streaming impossible).
    float wa[128];
    {
        const float4* wp4 = (const float4*)(W_hh + (size_t)grow * 512 + wave * 128);
        #pragma unroll
        for (int k = 0; k < 32; ++k) {
            float4 t4 = wp4[k];
            asm volatile("v_accvgpr_write_b32 %0, %1" : "=a"(wa[4 * k + 0]) : "v"(t4.x));
            asm volatile("v_accvgpr_write_b32 %0, %1" : "=a"(wa[4 * k + 1]) : "v"(t4.y));
            asm volatile("v_accvgpr_write_b32 %0, %1" : "=a"(wa[4 * k + 2]) : "v"(t4.z));
            asm volatile("v_accvgpr_write_b32 %0, %1" : "=a"(wa[4 * k + 3]) : "v"(t4.w));
        }
    }
    for (int idx = tid; idx < 64 * 19; idx += THREADS) {
        int rr = idx / 19, kk = idx - rr * 19;
        int gr2 = ((rr >> 4) << 9) + (w << 4) + (rr & 15);
        wih_lds[idx] = W_ih[gr2 * 19 + kk];
    }
    const float bsum = b_ih[grow] + b_hh[grow];

    float pj[6];
    #pragma unroll
    for (int o = 0; o < 6; ++o) pj[o] = 0.f;
    if (wave == 1 && lane < 16) {
        #pragma unroll
        for (int o = 0; o < 3; ++o) {
            pj[o]     = W_a[o * 512 + (w << 4) + lane];
            pj[o + 3] = W_b[o * 512 + (w << 4) + lane];
        }
    }

    float c_reg = 0.0f;
    int   thr   = 64;            // spins before memory-side rescue (self-lowering)
    __syncthreads();

    float sav = (wave == 0 && lane < 19) ? sa[lane] : 0.f;

    for (int t = 0; t < T_STEPS; ++t) {
        // ---- 0. gx on the fly (independent of h; overlaps the wait) ----
        float gxv = bsum;
        if (wave == 0) {
            #pragma unroll
            for (int k = 0; k < 19; ++k)
                gxv = fmaf(__shfl(sav, k), wih_lds[r * 19 + k], gxv);
        }
        float sav_n = 0.f;
        if (wave == 0 && lane < 19 && t + 1 < T_STEPS)
            sav_n = sa[(size_t)(t + 1) * 19 + lane];

        // ---- 1. poll-and-gather h_{t-1}: nt loads served by local XCD L2 ----
        if (t > 0) {
            ull* sp = hb + (size_t)((uint32)(t - 1) & (D_SLOTS - 1)) * 512 + 2 * tid;
            const uint32 tag = (uint32)t;
            u32x4 v;
            int spin = 0;
            for (;;) {
                poll16(sp, v);
                if (v.x == tag && v.z == tag) break;
                if (++spin >= thr) {             // memory-side rescue (proven path)
                    ull a = rescue_rmw(sp);
                    ull b = rescue_rmw(sp + 1);
                    if ((uint32)a == tag && (uint32)b == tag) {
                        v.x = (uint32)a; v.y = (uint32)(a >> 32);
                        v.z = (uint32)b; v.w = (uint32)(b >> 32);
                        break;
                    }
                    thr = 2;                      // fast path seems broken; adapt
                    spin = 0;
                }
            }
            *(float2*)&h_lds[2 * tid] =
                make_float2(__uint_as_float(v.y), __uint_as_float(v.w));
        } else {
            *(float2*)&h_lds[2 * tid] = make_float2(0.f, 0.f);
        }
        __syncthreads();

        float hprev = 0.f;
        if (wave == 1 && lane < 16) hprev = h_lds[(w << 4) + lane];

        // ---- 2. mat-vec partial: row r, cols [wave*128, wave*128+128) ----
        {
            const float4* hp4 = (const float4*)(h_lds + wave * 128);
            float ax = 0.f, ay = 0.f, az = 0.f, aw = 0.f;
            #pragma unroll
            for (int k = 0; k < 32; ++k) {
                float4 hv = hp4[k];
                float w0, w1, w2, w3;
                asm volatile("v_accvgpr_read_b32 %0, %1" : "=v"(w0) : "a"(wa[4 * k + 0]));
                asm volatile("v_accvgpr_read_b32 %0, %1" : "=v"(w1) : "a"(wa[4 * k + 1]));
                asm volatile("v_accvgpr_read_b32 %0, %1" : "=v"(w2) : "a"(wa[4 * k + 2]));
                asm volatile("v_accvgpr_read_b32 %0, %1" : "=v"(w3) : "a"(wa[4 * k + 3]));
                ax = fmaf(w0, hv.x, ax);
                ay = fmaf(w1, hv.y, ay);
                az = fmaf(w2, hv.z, az);
                aw = fmaf(w3, hv.w, aw);
            }
            part_lds[r * 5 + wave] = (ax + ay) + (az + aw);
        }
        __syncthreads();

        // ---- 3. gate assembly + cell update + publish (wave 0) ----
        if (wave == 0) {
            float pre = part_lds[r * 5] + part_lds[r * 5 + 1] +
                        part_lds[r * 5 + 2] + part_lds[r * 5 + 3] + gxv;

            const int g = r >> 4;
            float act = (g == 2) ? ftanh(pre) : fsig(pre);

            float i_v = __shfl(act, jloc);
            float f_v = __shfl(act, 16 + jloc);
            float g_v = __shfl(act, 32 + jloc);
            float o_v = __shfl(act, 48 + jloc);

            if (r < 16) {
                c_reg = f_v * c_reg + i_v * g_v;
                float hn = o_v * ftanh(c_reg);
                ull pk = ((ull)__float_as_uint(hn) << 32) | (ull)(uint32)(t + 1);
                // plain write-through store into the local XCD L2; fused tag IS the flag
                __hip_atomic_store(
                    &hb[(size_t)((uint32)t & (D_SLOTS - 1)) * 512 + (w << 4) + jloc],
                    pk, __ATOMIC_RELAXED, __HIP_MEMORY_SCOPE_WORKGROUP);
            }
        }
        // ---- 4. deferred output projection for out[t-1] (wave 1) ----
        else if (wave == 1 && lane < 16 && t > 0) {
            #pragma unroll
            for (int o = 0; o < 6; ++o) {
                float v = hprev * pj[o];
                v += __shfl_xor(v, 1);
                v += __shfl_xor(v, 2);
                v += __shfl_xor(v, 4);
                v += __shfl_xor(v, 8);
                if (lane == 0) {
                    int col = (o < 3) ? (3 * lstm + o) : (6 + 3 * lstm + (o - 3));
                    atomicAdd(&out[(size_t)(t - 1) * 12 + col], v);
                }
            }
        }
        sav = sav_n;
    }

    // ---- final projection for out[T-1] (nt-load spin + rescue) ----
    if (wave == 1 && lane < 16) {
        ull* src = hb + (size_t)((uint32)(T_STEPS - 1) & (D_SLOTS - 1)) * 512
                      + (w << 4) + lane;
        const uint32 tag = (uint32)T_STEPS;
        ull a;
        int spin = 0;
        for (;;) {
            u32x4 v;
            poll16(src, v);   // reads 16B; we use the first 8
            a = ((ull)v.y << 32) | v.x;
            if ((uint32)a == tag) break;
            if (++spin >= 64) {
                a = rescue_rmw(src);
                if ((uint32)a == tag) break;
                spin = 0;
            }
        }
        float hl = __uint_as_float((uint32)(a >> 32));
        #pragma unroll
        for (int o = 0; o < 6; ++o) {
            float s = hl * pj[o];
            s += __shfl_xor(s, 1);
            s += __shfl_xor(s, 2);
            s += __shfl_xor(s, 4);
            s += __shfl_xor(s, 8);
            if (lane == 0) {
                int col = (o < 3) ? (3 * lstm + o) : (6 + 3 * lstm + (o - 3));
                atomicAdd(&out[(size_t)(T_STEPS - 1) * 12 + col], s);
            }
        }
    }
}

__global__ void init_out(const float* __restrict__ b_xyz, const float* __restrict__ b_zeta,
                         const float* __restrict__ b_uvw, const float* __restrict__ b_pqr,
                         float* __restrict__ out)
{
    int idx = blockIdx.x * blockDim.x + threadIdx.x;
    if (idx < T_STEPS * 12) {
        int o = idx % 12;
        float v;
        if (o < 3)      v = b_xyz[o];
        else if (o < 6) v = b_zeta[o - 3];
        else if (o < 9) v = b_uvw[o - 6];
        else            v = b_pqr[o - 9];
        out[idx] = v;
    }
}

extern "C" void kernel_launch(void* const* d_in, const int* in_sizes, int n_in,
                              void* d_out, int out_size, void* d_ws, size_t ws_size,
                              hipStream_t stream)
{
    const float* sa    = (const float*)d_in[0];
    const float* W_ih1 = (const float*)d_in[1];
    const float* W_hh1 = (const float*)d_in[2];
    const float* b_ih1 = (const float*)d_in[3];
    const float* b_hh1 = (const float*)d_in[4];
    const float* W_ih2 = (const float*)d_in[5];
    const float* W_hh2 = (const float*)d_in[6];
    const float* b_ih2 = (const float*)d_in[7];
    const float* b_hh2 = (const float*)d_in[8];
    const float* W_xyz = (const float*)d_in[9];
    const float* b_xyz = (const float*)d_in[10];
    const float* W_zeta= (const float*)d_in[11];
    const float* b_zeta= (const float*)d_in[12];
    const float* W_uvw = (const float*)d_in[13];
    const float* b_uvw = (const float*)d_in[14];
    const float* W_pqr = (const float*)d_in[15];
    const float* b_pqr = (const float*)d_in[16];

    float*  out   = (float*)d_out;
    ull*    hrot  = (ull*)d_ws;
    uint32* claim = (uint32*)((char*)d_ws + 2 * D_SLOTS * 512 * sizeof(ull));

    // zero hrot tags + claim area every call (graph-replayed)
    hipMemsetAsync(d_ws, 0, 2 * D_SLOTS * 512 * sizeof(ull) + 128, stream);
    init_out<<<(T_STEPS * 12 + 255) / 256, 256, 0, stream>>>(b_xyz, b_zeta, b_uvw, b_pqr, out);

    lstm_persistent<<<NLAUNCH, THREADS, 0, stream>>>(
        sa, W_ih1, W_hh1, b_ih1, b_hh1, W_ih2, W_hh2, b_ih2, b_hh2,
        W_xyz, W_zeta, W_uvw, W_pqr, out, hrot, claim);
}

// Round 10
// 108408.411 us; speedup vs baseline: 4.2943x; 1.0471x over previous
//
#include <hip/hip_runtime.h>

#define T_STEPS 32768
#define THREADS 256
#define NLAUNCH 512   // WGs launched; 64 become workers, rest exit
#define D_SLOTS 4     // h rotation depth (max producer skew = 1)

typedef unsigned int uint32;
typedef unsigned long long ull;
typedef unsigned int u32x4 __attribute__((ext_vector_type(4)));

// ws layout:
// [0, 32768)       : hrot = ull[2 lstm][D_SLOTS][512]; each ull = {lo: tag=t+1, hi: f32 h}
// [32768, 32896)   : claim area (32 uints)

__device__ inline float fsig(float x) {
    return __builtin_amdgcn_rcpf(1.f + __expf(-x));
}
__device__ inline float ftanh(float x) {
    return 1.f - 2.f * __builtin_amdgcn_rcpf(1.f + __expf(2.f * x));
}

// Non-temporal poll load: nt = no-allocate in L1, so hbuf lines are NEVER
// resident in L1 (no other access path allocates them either) -> every poll
// is served by the XCD-local L2, which the producer's write-through store
// updated. sc0 additionally requests L1 bypass. No RMW -> no memory-side trip.
__device__ inline void poll16(const ull* p, u32x4& v) {
    asm volatile("global_load_dwordx4 %0, %1, off sc0 nt\n\t"
                 "s_waitcnt vmcnt(0)"
                 : "=v"(v) : "v"(p) : "memory");
}

// claim-phase primitives (agent scope; startup-only) + rescue RMW (memory-side,
// slow but round-7-proven fresh)
__device__ inline uint32 a_add(uint32* p, uint32 v) {
    return __hip_atomic_fetch_add(p, v, __ATOMIC_RELAXED, __HIP_MEMORY_SCOPE_AGENT);
}
__device__ inline uint32 a_ld(const uint32* p) {
    return __hip_atomic_load(p, __ATOMIC_RELAXED, __HIP_MEMORY_SCOPE_AGENT);
}
__device__ inline void a_st(uint32* p, uint32 v) {
    __hip_atomic_store(p, v, __ATOMIC_RELAXED, __HIP_MEMORY_SCOPE_AGENT);
}
__device__ inline ull rescue_rmw(ull* p) {
    return __hip_atomic_fetch_add(p, 0ull, __ATOMIC_RELAXED, __HIP_MEMORY_SCOPE_AGENT);
}

__global__ __launch_bounds__(THREADS, 2)
void lstm_persistent(const float* __restrict__ sa,
                     const float* __restrict__ W_ih1, const float* __restrict__ W_hh1,
                     const float* __restrict__ b_ih1, const float* __restrict__ b_hh1,
                     const float* __restrict__ W_ih2, const float* __restrict__ W_hh2,
                     const float* __restrict__ b_ih2, const float* __restrict__ b_hh2,
                     const float* __restrict__ W_xyz, const float* __restrict__ W_zeta,
                     const float* __restrict__ W_uvw, const float* __restrict__ W_pqr,
                     float* __restrict__ out, ull* hrot, uint32* claim)
{
    const int tid  = threadIdx.x;
    const int wave = tid >> 6;
    const int lane = tid & 63;

    __shared__ int s_lstm, s_w;

    // ---- XCD-local role claiming (thread 0); agent-scope, startup-only ----
    if (tid == 0) {
        uint32 xcc;
        asm volatile("s_getreg_b32 %0, hwreg(HW_REG_XCC_ID)" : "=s"(xcc));
        xcc &= 7;
        uint32* cnt     = claim;            // [0..7]
        uint32* rankcnt = claim + 8;
        uint32* grank   = claim + 16;       // [xcd*2 + g]

        int lstm = -1, w = 0;
        uint32 slot = a_add(&cnt[xcc], 1);
        if (slot < 64) {
            uint32 g = slot >> 5, role = slot & 31;
            uint32* gr = &grank[xcc * 2 + g];
            if (role == 31) {                 // completer: group is full
                uint32 rank = a_add(rankcnt, 1);
                uint32 val  = (rank < 2) ? (rank + 1) : 0xFEu;
                a_st(gr, val);
                if (val != 0xFEu) { lstm = (int)rank; w = 31; }
            } else {                          // spinner
                for (;;) {
                    uint32 v = a_ld(gr);
                    if (v != 0) {
                        if (v != 0xFEu) { lstm = (int)v - 1; w = (int)role; }
                        break;
                    }
                    if (a_ld(rankcnt) >= 2 && a_ld(&cnt[xcc]) < (g + 1) * 32)
                        break;                // group can never get a valid rank
                }
            }
        }
        s_lstm = lstm; s_w = w;
    }
    __syncthreads();
    const int lstm = s_lstm;
    const int w    = s_w;
    if (lstm < 0) return;

    const float* W_ih = lstm ? W_ih2 : W_ih1;
    const float* W_hh = lstm ? W_hh2 : W_hh1;
    const float* b_ih = lstm ? b_ih2 : b_ih1;
    const float* b_hh = lstm ? b_hh2 : b_hh1;
    const float* W_a  = lstm ? W_zeta : W_xyz;
    const float* W_b  = lstm ? W_pqr  : W_uvw;

    ull* hb = hrot + (size_t)lstm * D_SLOTS * 512;

    __shared__ __align__(16) float h_lds[512];
    __shared__ float part_lds[64 * 5];
    __shared__ float wih_lds[64 * 19];

    const int r    = lane;
    const int jloc = r & 15;
    const int grow = ((r >> 4) << 9) + (w << 4) + jloc;

    // W_hh slice: 128 weights / thread, held in AGPRs (explicit accvgpr ops;
    // register-class constraints make L2/scratch re-streaming impossible).
    float wa[128];
    {
        const float4* wp4 = (const float4*)(W_hh + (size_t)grow * 512 + wave * 128);
        #pragma unroll
        for (int k = 0; k < 32; ++k) {
            float4 t4 = wp4[k];
            asm volatile("v_accvgpr_write_b32 %0, %1" : "=a"(wa[4 * k + 0]) : "v"(t4.x));
            asm volatile("v_accvgpr_write_b32 %0, %1" : "=a"(wa[4 * k + 1]) : "v"(t4.y));
            asm volatile("v_accvgpr_write_b32 %0, %1" : "=a"(wa[4 * k + 2]) : "v"(t4.z));
            asm volatile("v_accvgpr_write_b32 %0, %1" : "=a"(wa[4 * k + 3]) : "v"(t4.w));
        }
    }
    for (int idx = tid; idx < 64 * 19; idx += THREADS) {
        int rr = idx / 19, kk = idx - rr * 19;
        int gr2 = ((rr >> 4) << 9) + (w << 4) + (rr & 15);
        wih_lds[idx] = W_ih[gr2 * 19 + kk];
    }
    const float bsum = b_ih[grow] + b_hh[grow];

    float pj[6];
    #pragma unroll
    for (int o = 0; o < 6; ++o) pj[o] = 0.f;
    if (wave == 1 && lane < 16) {
        #pragma unroll
        for (int o = 0; o < 3; ++o) {
            pj[o]     = W_a[o * 512 + (w << 4) + lane];
            pj[o + 3] = W_b[o * 512 + (w << 4) + lane];
        }
    }

    float c_reg = 0.0f;
    int   thr   = 64;            // spins before memory-side rescue (self-lowering)
    __syncthreads();

    float sav = (wave == 0 && lane < 19) ? sa[lane] : 0.f;

    for (int t = 0; t < T_STEPS; ++t) {
        // ---- 0. gx on the fly (independent of h; overlaps the wait) ----
        float gxv = bsum;
        if (wave == 0) {
            #pragma unroll
            for (int k = 0; k < 19; ++k)
                gxv = fmaf(__shfl(sav, k), wih_lds[r * 19 + k], gxv);
        }
        float sav_n = 0.f;
        if (wave == 0 && lane < 19 && t + 1 < T_STEPS)
            sav_n = sa[(size_t)(t + 1) * 19 + lane];

        // ---- 1. poll-and-gather h_{t-1}: nt loads served by local XCD L2 ----
        if (t > 0) {
            ull* sp = hb + (size_t)((uint32)(t - 1) & (D_SLOTS - 1)) * 512 + 2 * tid;
            const uint32 tag = (uint32)t;
            u32x4 v;
            int spin = 0;
            for (;;) {
                poll16(sp, v);
                if (v.x == tag && v.z == tag) break;
                if (++spin >= thr) {             // memory-side rescue (proven path)
                    ull a = rescue_rmw(sp);
                    ull b = rescue_rmw(sp + 1);
                    if ((uint32)a == tag && (uint32)b == tag) {
                        v.x = (uint32)a; v.y = (uint32)(a >> 32);
                        v.z = (uint32)b; v.w = (uint32)(b >> 32);
                        break;
                    }
                    thr = 2;                      // fast path seems broken; adapt
                    spin = 0;
                }
            }
            *(float2*)&h_lds[2 * tid] =
                make_float2(__uint_as_float(v.y), __uint_as_float(v.w));
        } else {
            *(float2*)&h_lds[2 * tid] = make_float2(0.f, 0.f);
        }
        __syncthreads();

        float hprev = 0.f;
        if (wave == 1 && lane < 16) hprev = h_lds[(w << 4) + lane];

        // ---- 2. mat-vec partial: row r, cols [wave*128, wave*128+128) ----
        {
            const float4* hp4 = (const float4*)(h_lds + wave * 128);
            float ax = 0.f, ay = 0.f, az = 0.f, aw = 0.f;
            #pragma unroll
            for (int k = 0; k < 32; ++k) {
                float4 hv = hp4[k];
                float w0, w1, w2, w3;
                asm volatile("v_accvgpr_read_b32 %0, %1" : "=v"(w0) : "a"(wa[4 * k + 0]));
                asm volatile("v_accvgpr_read_b32 %0, %1" : "=v"(w1) : "a"(wa[4 * k + 1]));
                asm volatile("v_accvgpr_read_b32 %0, %1" : "=v"(w2) : "a"(wa[4 * k + 2]));
                asm volatile("v_accvgpr_read_b32 %0, %1" : "=v"(w3) : "a"(wa[4 * k + 3]));
                ax = fmaf(w0, hv.x, ax);
                ay = fmaf(w1, hv.y, ay);
                az = fmaf(w2, hv.z, az);
                aw = fmaf(w3, hv.w, aw);
            }
            part_lds[r * 5 + wave] = (ax + ay) + (az + aw);
        }
        __syncthreads();

        // ---- 3. gate assembly + cell update + publish (wave 0) ----
        if (wave == 0) {
            float pre = part_lds[r * 5] + part_lds[r * 5 + 1] +
                        part_lds[r * 5 + 2] + part_lds[r * 5 + 3] + gxv;

            const int g = r >> 4;
            float act = (g == 2) ? ftanh(pre) : fsig(pre);

            float i_v = __shfl(act, jloc);
            float f_v = __shfl(act, 16 + jloc);
            float g_v = __shfl(act, 32 + jloc);
            float o_v = __shfl(act, 48 + jloc);

            if (r < 16) {
                c_reg = f_v * c_reg + i_v * g_v;
                float hn = o_v * ftanh(c_reg);
                ull pk = ((ull)__float_as_uint(hn) << 32) | (ull)(uint32)(t + 1);
                // plain write-through store into the local XCD L2; fused tag IS the flag
                __hip_atomic_store(
                    &hb[(size_t)((uint32)t & (D_SLOTS - 1)) * 512 + (w << 4) + jloc],
                    pk, __ATOMIC_RELAXED, __HIP_MEMORY_SCOPE_WORKGROUP);
            }
        }
        // ---- 4. deferred output projection for out[t-1] (wave 1) ----
        else if (wave == 1 && lane < 16 && t > 0) {
            #pragma unroll
            for (int o = 0; o < 6; ++o) {
                float v = hprev * pj[o];
                v += __shfl_xor(v, 1);
                v += __shfl_xor(v, 2);
                v += __shfl_xor(v, 4);
                v += __shfl_xor(v, 8);
                if (lane == 0) {
                    int col = (o < 3) ? (3 * lstm + o) : (6 + 3 * lstm + (o - 3));
                    atomicAdd(&out[(size_t)(t - 1) * 12 + col], v);
                }
            }
        }
        sav = sav_n;
    }

    // ---- final projection for out[T-1] (nt-load spin + rescue) ----
    if (wave == 1 && lane < 16) {
        ull* src = hb + (size_t)((uint32)(T_STEPS - 1) & (D_SLOTS - 1)) * 512
                      + (w << 4) + lane;
        const uint32 tag = (uint32)T_STEPS;
        ull a;
        int spin = 0;
        for (;;) {
            u32x4 v;
            poll16(src, v);   // reads 16B; we use the first 8
            a = ((ull)v.y << 32) | v.x;
            if ((uint32)a == tag) break;
            if (++spin >= 64) {
                a = rescue_rmw(src);
                if ((uint32)a == tag) break;
                spin = 0;
            }
        }
        float hl = __uint_as_float((uint32)(a >> 32));
        #pragma unroll
        for (int o = 0; o < 6; ++o) {
            float s = hl * pj[o];
            s += __shfl_xor(s, 1);
            s += __shfl_xor(s, 2);
            s += __shfl_xor(s, 4);
            s += __shfl_xor(s, 8);
            if (lane == 0) {
                int col = (o < 3) ? (3 * lstm + o) : (6 + 3 * lstm + (o - 3));
                atomicAdd(&out[(size_t)(T_STEPS - 1) * 12 + col], s);
            }
        }
    }
}

__global__ void init_out(const float* __restrict__ b_xyz, const float* __restrict__ b_zeta,
                         const float* __restrict__ b_uvw, const float* __restrict__ b_pqr,
                         float* __restrict__ out)
{
    int idx = blockIdx.x * blockDim.x + threadIdx.x;
    if (idx < T_STEPS * 12) {
        int o = idx % 12;
        float v;
        if (o < 3)      v = b_xyz[o];
        else if (o < 6) v = b_zeta[o - 3];
        else if (o < 9) v = b_uvw[o - 6];
        else            v = b_pqr[o - 9];
        out[idx] = v;
    }
}

extern "C" void kernel_launch(void* const* d_in, const int* in_sizes, int n_in,
                              void* d_out, int out_size, void* d_ws, size_t ws_size,
                              hipStream_t stream)
{
    const float* sa    = (const float*)d_in[0];
    const float* W_ih1 = (const float*)d_in[1];
    const float* W_hh1 = (const float*)d_in[2];
    const float* b_ih1 = (const float*)d_in[3];
    const float* b_hh1 = (const float*)d_in[4];
    const float* W_ih2 = (const float*)d_in[5];
    const float* W_hh2 = (const float*)d_in[6];
    const float* b_ih2 = (const float*)d_in[7];
    const float* b_hh2 = (const float*)d_in[8];
    const float* W_xyz = (const float*)d_in[9];
    const float* b_xyz = (const float*)d_in[10];
    const float* W_zeta= (const float*)d_in[11];
    const float* b_zeta= (const float*)d_in[12];
    const float* W_uvw = (const float*)d_in[13];
    const float* b_uvw = (const float*)d_in[14];
    const float* W_pqr = (const float*)d_in[15];
    const float* b_pqr = (const float*)d_in[16];

    float*  out   = (float*)d_out;
    ull*    hrot  = (ull*)d_ws;
    uint32* claim = (uint32*)((char*)d_ws + 2 * D_SLOTS * 512 * sizeof(ull));

    // zero hrot tags + claim area every call (graph-replayed)
    hipMemsetAsync(d_ws, 0, 2 * D_SLOTS * 512 * sizeof(ull) + 128, stream);
    init_out<<<(T_STEPS * 12 + 255) / 256, 256, 0, stream>>>(b_xyz, b_zeta, b_uvw, b_pqr, out);

    lstm_persistent<<<NLAUNCH, THREADS, 0, stream>>>(
        sa, W_ih1, W_hh1, b_ih1, b_hh1, W_ih2, W_hh2, b_ih2, b_hh2,
        W_xyz, W_zeta, W_uvw, W_pqr, out, hrot, claim);
}

// Round 11
// 94429.987 us; speedup vs baseline: 4.9300x; 1.1480x over previous
//
#include <hip/hip_runtime.h>

#define T_STEPS 32768
#define THREADS 256
#define NLAUNCH 256   // 1 block per CU (register-forced exclusivity); 64 become workers
#define D_SLOTS 4     // h rotation depth (max producer skew = 1)

typedef unsigned int uint32;
typedef unsigned long long ull;
typedef unsigned int u32x4 __attribute__((ext_vector_type(4)));

// ws layout:
// [0, 32768)       : hrot = ull[2 lstm][D_SLOTS][512]; each ull = {lo: tag=t+1, hi: f32 h}
// [32768, 32896)   : claim area (32 uints): [0..7] cnt/XCD, [8] rankcnt, [16..23] grank/XCD

__device__ inline float fsig(float x) {
    return __builtin_amdgcn_rcpf(1.f + __expf(-x));
}
__device__ inline float ftanh(float x) {
    return 1.f - 2.f * __builtin_amdgcn_rcpf(1.f + __expf(2.f * x));
}

// Non-temporal poll load: no-allocate in L1 -> hbuf lines never live in L1 ->
// served by the XCD-local L2 that producers write through to. (R10-proven:
// zero rescues across 8.4M polls.)
__device__ inline void poll16(const ull* p, u32x4& v) {
    asm volatile("global_load_dwordx4 %0, %1, off sc0 nt\n\t"
                 "s_waitcnt vmcnt(0)"
                 : "=v"(v) : "v"(p) : "memory");
}

// claim-phase primitives (agent scope; startup-only) + memory-side rescue RMW
__device__ inline uint32 a_add(uint32* p, uint32 v) {
    return __hip_atomic_fetch_add(p, v, __ATOMIC_RELAXED, __HIP_MEMORY_SCOPE_AGENT);
}
__device__ inline uint32 a_ld(const uint32* p) {
    return __hip_atomic_load(p, __ATOMIC_RELAXED, __HIP_MEMORY_SCOPE_AGENT);
}
__device__ inline void a_st(uint32* p, uint32 v) {
    __hip_atomic_store(p, v, __ATOMIC_RELAXED, __HIP_MEMORY_SCOPE_AGENT);
}
__device__ inline ull rescue_rmw(ull* p) {
    return __hip_atomic_fetch_add(p, 0ull, __ATOMIC_RELAXED, __HIP_MEMORY_SCOPE_AGENT);
}

__global__ __launch_bounds__(THREADS, 1)
void lstm_persistent(const float* __restrict__ sa,
                     const float* __restrict__ W_ih1, const float* __restrict__ W_hh1,
                     const float* __restrict__ b_ih1, const float* __restrict__ b_hh1,
                     const float* __restrict__ W_ih2, const float* __restrict__ W_hh2,
                     const float* __restrict__ b_ih2, const float* __restrict__ b_hh2,
                     const float* __restrict__ W_xyz, const float* __restrict__ W_zeta,
                     const float* __restrict__ W_uvw, const float* __restrict__ W_pqr,
                     float* __restrict__ out, ull* hrot, uint32* claim)
{
    const int tid  = threadIdx.x;
    const int wave = tid >> 6;
    const int lane = tid & 63;

    __shared__ int s_lstm, s_w;

    // ---- per-XCD role claiming: one LSTM per XCD (thread 0) ----
    if (tid == 0) {
        uint32 xcc;
        asm volatile("s_getreg_b32 %0, hwreg(HW_REG_XCC_ID)" : "=s"(xcc));
        xcc &= 7;
        uint32* cnt     = claim;            // [0..7]
        uint32* rankcnt = claim + 8;
        uint32* grank   = claim + 16;       // [xcd]

        int lstm = -1, w = 0;
        uint32 slot = a_add(&cnt[xcc], 1);
        if (slot < 32) {
            w = (int)slot;
            if (slot == 31) {               // completer: this XCD's group is full
                uint32 rank = a_add(rankcnt, 1);
                a_st(&grank[xcc], (rank < 2) ? (rank + 1) : 0xFEu);
            }
            uint32 v;
            long spins = 0;
            for (;;) {
                v = a_ld(&grank[xcc]);
                if (v != 0) break;
                // escape only in pathological dispatch (XCD got <32 blocks):
                // once both ranks are taken elsewhere and nothing arrives, exit.
                if (a_ld(rankcnt) >= 2 && ++spins > 200000) { v = 0xFEu; break; }
            }
            if (v != 0xFEu) lstm = (int)v - 1;
        }
        s_lstm = lstm; s_w = w;
    }
    __syncthreads();
    const int lstm = s_lstm;
    const int w    = s_w;
    if (lstm < 0) return;

    const float* W_ih = lstm ? W_ih2 : W_ih1;
    const float* W_hh = lstm ? W_hh2 : W_hh1;
    const float* b_ih = lstm ? b_ih2 : b_ih1;
    const float* b_hh = lstm ? b_hh2 : b_hh1;
    const float* W_a  = lstm ? W_zeta : W_xyz;
    const float* W_b  = lstm ? W_pqr  : W_uvw;

    ull* hb = hrot + (size_t)lstm * D_SLOTS * 512;

    __shared__ __align__(16) float h_lds[512];
    __shared__ float part_lds[64 * 5];
    __shared__ float wih_lds[64 * 19];

    const int r    = lane;
    const int jloc = r & 15;
    const int grow = ((r >> 4) << 9) + (w << 4) + jloc;

    // W_hh slice: 128 weights / thread in AGPRs (R10-proven resident).
    float wa[128];
    {
        const float4* wp4 = (const float4*)(W_hh + (size_t)grow * 512 + wave * 128);
        #pragma unroll
        for (int k = 0; k < 32; ++k) {
            float4 t4 = wp4[k];
            asm volatile("v_accvgpr_write_b32 %0, %1" : "=a"(wa[4 * k + 0]) : "v"(t4.x));
            asm volatile("v_accvgpr_write_b32 %0, %1" : "=a"(wa[4 * k + 1]) : "v"(t4.y));
            asm volatile("v_accvgpr_write_b32 %0, %1" : "=a"(wa[4 * k + 2]) : "v"(t4.z));
            asm volatile("v_accvgpr_write_b32 %0, %1" : "=a"(wa[4 * k + 3]) : "v"(t4.w));
        }
    }
    for (int idx = tid; idx < 64 * 19; idx += THREADS) {
        int rr = idx / 19, kk = idx - rr * 19;
        int gr2 = ((rr >> 4) << 9) + (w << 4) + (rr & 15);
        wih_lds[idx] = W_ih[gr2 * 19 + kk];
    }
    const float bsum = b_ih[grow] + b_hh[grow];

    // AGPR ballast: +16 live accregs push total regs/wave past 256 so the HW
    // can host only 1 wave/SIMD -> exactly one WG per CU (issue-exclusive).
    float ball[16];
    #pragma unroll
    for (int k = 0; k < 16; ++k)
        asm volatile("v_accvgpr_write_b32 %0, %1" : "=a"(ball[k]) : "v"(bsum));

    float pj[6];
    #pragma unroll
    for (int o = 0; o < 6; ++o) pj[o] = 0.f;
    if (wave == 1 && lane < 16) {
        #pragma unroll
        for (int o = 0; o < 3; ++o) {
            pj[o]     = W_a[o * 512 + (w << 4) + lane];
            pj[o + 3] = W_b[o * 512 + (w << 4) + lane];
        }
    }

    float c_reg = 0.0f;
    int   thr   = 64;            // spins before memory-side rescue
    __syncthreads();

    float sav = (wave == 0 && lane < 19) ? sa[lane] : 0.f;

    for (int t = 0; t < T_STEPS; ++t) {
        // ---- 0. gx on the fly (independent of h; overlaps the wait) ----
        float gxv = bsum;
        if (wave == 0) {
            #pragma unroll
            for (int k = 0; k < 19; ++k)
                gxv = fmaf(__shfl(sav, k), wih_lds[r * 19 + k], gxv);
        }
        float sav_n = 0.f;
        if (wave == 0 && lane < 19 && t + 1 < T_STEPS)
            sav_n = sa[(size_t)(t + 1) * 19 + lane];

        // ---- 1. poll-and-gather h_{t-1}: nt loads served by local XCD L2 ----
        if (t > 0) {
            ull* sp = hb + (size_t)((uint32)(t - 1) & (D_SLOTS - 1)) * 512 + 2 * tid;
            const uint32 tag = (uint32)t;
            u32x4 v;
            int spin = 0;
            for (;;) {
                poll16(sp, v);
                if (v.x == tag && v.z == tag) break;
                if (++spin >= thr) {             // memory-side rescue (proven path)
                    ull a = rescue_rmw(sp);
                    ull b = rescue_rmw(sp + 1);
                    if ((uint32)a == tag && (uint32)b == tag) {
                        v.x = (uint32)a; v.y = (uint32)(a >> 32);
                        v.z = (uint32)b; v.w = (uint32)(b >> 32);
                        break;
                    }
                    thr = 2;                      // fast path seems broken; adapt
                    spin = 0;
                }
            }
            *(float2*)&h_lds[2 * tid] =
                make_float2(__uint_as_float(v.y), __uint_as_float(v.w));
        } else {
            *(float2*)&h_lds[2 * tid] = make_float2(0.f, 0.f);
        }
        __syncthreads();

        float hprev = 0.f;
        if (wave == 1 && lane < 16) hprev = h_lds[(w << 4) + lane];

        // ---- 2. mat-vec partial: row r, cols [wave*128, wave*128+128) ----
        {
            const float4* hp4 = (const float4*)(h_lds + wave * 128);
            float ax = 0.f, ay = 0.f, az = 0.f, aw = 0.f;
            #pragma unroll
            for (int k = 0; k < 32; ++k) {
                float4 hv = hp4[k];
                float w0, w1, w2, w3;
                asm volatile("v_accvgpr_read_b32 %0, %1" : "=v"(w0) : "a"(wa[4 * k + 0]));
                asm volatile("v_accvgpr_read_b32 %0, %1" : "=v"(w1) : "a"(wa[4 * k + 1]));
                asm volatile("v_accvgpr_read_b32 %0, %1" : "=v"(w2) : "a"(wa[4 * k + 2]));
                asm volatile("v_accvgpr_read_b32 %0, %1" : "=v"(w3) : "a"(wa[4 * k + 3]));
                ax = fmaf(w0, hv.x, ax);
                ay = fmaf(w1, hv.y, ay);
                az = fmaf(w2, hv.z, az);
                aw = fmaf(w3, hv.w, aw);
            }
            part_lds[r * 5 + wave] = (ax + ay) + (az + aw);
        }
        __syncthreads();

        // ---- 3. gate assembly + cell update + publish (wave 0) ----
        if (wave == 0) {
            float pre = part_lds[r * 5] + part_lds[r * 5 + 1] +
                        part_lds[r * 5 + 2] + part_lds[r * 5 + 3] + gxv;

            const int g = r >> 4;
            float act = (g == 2) ? ftanh(pre) : fsig(pre);

            float i_v = __shfl(act, jloc);
            float f_v = __shfl(act, 16 + jloc);
            float g_v = __shfl(act, 32 + jloc);
            float o_v = __shfl(act, 48 + jloc);

            if (r < 16) {
                c_reg = f_v * c_reg + i_v * g_v;
                float hn = o_v * ftanh(c_reg);
                ull pk = ((ull)__float_as_uint(hn) << 32) | (ull)(uint32)(t + 1);
                // plain write-through store into the local XCD L2; fused tag IS the flag
                __hip_atomic_store(
                    &hb[(size_t)((uint32)t & (D_SLOTS - 1)) * 512 + (w << 4) + jloc],
                    pk, __ATOMIC_RELAXED, __HIP_MEMORY_SCOPE_WORKGROUP);
            }
        }
        // ---- 4. deferred output projection for out[t-1] (wave 1) ----
        else if (wave == 1 && lane < 16 && t > 0) {
            #pragma unroll
            for (int o = 0; o < 6; ++o) {
                float v = hprev * pj[o];
                v += __shfl_xor(v, 1);
                v += __shfl_xor(v, 2);
                v += __shfl_xor(v, 4);
                v += __shfl_xor(v, 8);
                if (lane == 0) {
                    int col = (o < 3) ? (3 * lstm + o) : (6 + 3 * lstm + (o - 3));
                    atomicAdd(&out[(size_t)(t - 1) * 12 + col], v);
                }
            }
        }
        sav = sav_n;
    }

    // ---- final projection for out[T-1] (nt-load spin + rescue) ----
    if (wave == 1 && lane < 16) {
        ull* src = hb + (size_t)((uint32)(T_STEPS - 1) & (D_SLOTS - 1)) * 512
                      + (w << 4) + lane;
        const uint32 tag = (uint32)T_STEPS;
        ull a;
        int spin = 0;
        for (;;) {
            u32x4 v;
            poll16(src, v);   // reads 16B; we use the first 8
            a = ((ull)v.y << 32) | v.x;
            if ((uint32)a == tag) break;
            if (++spin >= 64) {
                a = rescue_rmw(src);
                if ((uint32)a == tag) break;
                spin = 0;
            }
        }
        float hl = __uint_as_float((uint32)(a >> 32));
        #pragma unroll
        for (int o = 0; o < 6; ++o) {
            float s = hl * pj[o];
            s += __shfl_xor(s, 1);
            s += __shfl_xor(s, 2);
            s += __shfl_xor(s, 4);
            s += __shfl_xor(s, 8);
            if (lane == 0) {
                int col = (o < 3) ? (3 * lstm + o) : (6 + 3 * lstm + (o - 3));
                atomicAdd(&out[(size_t)(T_STEPS - 1) * 12 + col], s);
            }
        }
    }

    // keep ballast AGPRs live through the whole kernel (branch never taken:
    // lstm is in {-1,0,1}; compiler cannot prove it)
    if (lstm < -1) {
        float s = 0.f;
        #pragma unroll
        for (int k = 0; k < 16; ++k) {
            float tv;
            asm volatile("v_accvgpr_read_b32 %0, %1" : "=v"(tv) : "a"(ball[k]));
            s += tv;
        }
        ((float*)claim)[31] = s;
    }
}

__global__ void init_out(const float* __restrict__ b_xyz, const float* __restrict__ b_zeta,
                         const float* __restrict__ b_uvw, const float* __restrict__ b_pqr,
                         float* __restrict__ out)
{
    int idx = blockIdx.x * blockDim.x + threadIdx.x;
    if (idx < T_STEPS * 12) {
        int o = idx % 12;
        float v;
        if (o < 3)      v = b_xyz[o];
        else if (o < 6) v = b_zeta[o - 3];
        else if (o < 9) v = b_uvw[o - 6];
        else            v = b_pqr[o - 9];
        out[idx] = v;
    }
}

extern "C" void kernel_launch(void* const* d_in, const int* in_sizes, int n_in,
                              void* d_out, int out_size, void* d_ws, size_t ws_size,
                              hipStream_t stream)
{
    const float* sa    = (const float*)d_in[0];
    const float* W_ih1 = (const float*)d_in[1];
    const float* W_hh1 = (const float*)d_in[2];
    const float* b_ih1 = (const float*)d_in[3];
    const float* b_hh1 = (const float*)d_in[4];
    const float* W_ih2 = (const float*)d_in[5];
    const float* W_hh2 = (const float*)d_in[6];
    const float* b_ih2 = (const float*)d_in[7];
    const float* b_hh2 = (const float*)d_in[8];
    const float* W_xyz = (const float*)d_in[9];
    const float* b_xyz = (const float*)d_in[10];
    const float* W_zeta= (const float*)d_in[11];
    const float* b_zeta= (const float*)d_in[12];
    const float* W_uvw = (const float*)d_in[13];
    const float* b_uvw = (const float*)d_in[14];
    const float* W_pqr = (const float*)d_in[15];
    const float* b_pqr = (const float*)d_in[16];

    float*  out   = (float*)d_out;
    ull*    hrot  = (ull*)d_ws;
    uint32* claim = (uint32*)((char*)d_ws + 2 * D_SLOTS * 512 * sizeof(ull));

    // zero hrot tags + claim area every call (graph-replayed)
    hipMemsetAsync(d_ws, 0, 2 * D_SLOTS * 512 * sizeof(ull) + 128, stream);
    init_out<<<(T_STEPS * 12 + 255) / 256, 256, 0, stream>>>(b_xyz, b_zeta, b_uvw, b_pqr, out);

    lstm_persistent<<<NLAUNCH, THREADS, 0, stream>>>(
        sa, W_ih1, W_hh1, b_ih1, b_hh1, W_ih2, W_hh2, b_ih2, b_hh2,
        W_xyz, W_zeta, W_uvw, W_pqr, out, hrot, claim);
}

// Round 12
// 77582.538 us; speedup vs baseline: 6.0006x; 1.2172x over previous
//
#include <hip/hip_runtime.h>

#define T_STEPS 32768
#define THREADS 256
#define NLAUNCH 256   // 1 block per CU (register-forced exclusivity); 64 become workers
#define D_SLOTS 4     // h rotation depth

typedef unsigned int uint32;
typedef unsigned long long ull;
typedef unsigned int u32x4 __attribute__((ext_vector_type(4)));

// ws layout:
// [0, 32768)       : hrot = ull[2 lstm][D_SLOTS][512]; each ull = {lo: tag=t+1, hi: f32 h}
// [32768, 32896)   : claim area (32 uints): [0..7] cnt/XCD, [8] rankcnt, [16..23] grank/XCD

__device__ inline float fsig(float x) {
    return __builtin_amdgcn_rcpf(1.f + __expf(-x));
}
__device__ inline float ftanh(float x) {
    return 1.f - 2.f * __builtin_amdgcn_rcpf(1.f + __expf(2.f * x));
}
__device__ inline float wred64(float x) {
    x += __shfl_xor(x, 1);  x += __shfl_xor(x, 2);  x += __shfl_xor(x, 4);
    x += __shfl_xor(x, 8);  x += __shfl_xor(x, 16); x += __shfl_xor(x, 32);
    return x;
}

// Non-temporal poll load (R10-proven: zero rescues over 8.4M polls):
// nt = no-allocate in L1 -> line served by the XCD-local L2 that producers
// write through to.
__device__ inline void poll16(const ull* p, u32x4& v) {
    asm volatile("global_load_dwordx4 %0, %1, off sc0 nt\n\t"
                 "s_waitcnt vmcnt(0)"
                 : "=v"(v) : "v"(p) : "memory");
}

__device__ inline uint32 a_add(uint32* p, uint32 v) {
    return __hip_atomic_fetch_add(p, v, __ATOMIC_RELAXED, __HIP_MEMORY_SCOPE_AGENT);
}
__device__ inline uint32 a_ld(const uint32* p) {
    return __hip_atomic_load(p, __ATOMIC_RELAXED, __HIP_MEMORY_SCOPE_AGENT);
}
__device__ inline void a_st(uint32* p, uint32 v) {
    __hip_atomic_store(p, v, __ATOMIC_RELAXED, __HIP_MEMORY_SCOPE_AGENT);
}
__device__ inline ull rescue_rmw(ull* p) {
    return __hip_atomic_fetch_add(p, 0ull, __ATOMIC_RELAXED, __HIP_MEMORY_SCOPE_AGENT);
}

__global__ __launch_bounds__(THREADS, 1)
void lstm_persistent(const float* __restrict__ sa,
                     const float* __restrict__ W_ih1, const float* __restrict__ W_hh1,
                     const float* __restrict__ b_ih1, const float* __restrict__ b_hh1,
                     const float* __restrict__ W_ih2, const float* __restrict__ W_hh2,
                     const float* __restrict__ b_ih2, const float* __restrict__ b_hh2,
                     const float* __restrict__ W_xyz, const float* __restrict__ b_xyz,
                     const float* __restrict__ W_zeta, const float* __restrict__ b_zeta,
                     const float* __restrict__ W_uvw, const float* __restrict__ b_uvw,
                     const float* __restrict__ W_pqr, const float* __restrict__ b_pqr,
                     float* __restrict__ out, ull* hrot, uint32* claim)
{
    const int tid  = threadIdx.x;
    const int wv   = tid >> 6;    // wave 0..3
    const int lane = tid & 63;

    __shared__ int s_lstm, s_w;

    // ---- per-XCD role claiming: one LSTM per XCD (thread 0; R11-proven) ----
    if (tid == 0) {
        uint32 xcc;
        asm volatile("s_getreg_b32 %0, hwreg(HW_REG_XCC_ID)" : "=s"(xcc));
        xcc &= 7;
        uint32* cnt     = claim;
        uint32* rankcnt = claim + 8;
        uint32* grank   = claim + 16;

        int lstm = -1, w = 0;
        uint32 slot = a_add(&cnt[xcc], 1);
        if (slot < 32) {
            w = (int)slot;
            if (slot == 31) {
                uint32 rank = a_add(rankcnt, 1);
                a_st(&grank[xcc], (rank < 2) ? (rank + 1) : 0xFEu);
            }
            uint32 g;
            long spins = 0;
            for (;;) {
                g = a_ld(&grank[xcc]);
                if (g != 0) break;
                if (a_ld(rankcnt) >= 2 && ++spins > 200000) { g = 0xFEu; break; }
            }
            if (g != 0xFEu) lstm = (int)g - 1;
        }
        s_lstm = lstm; s_w = w;
    }
    __syncthreads();
    const int lstm = s_lstm;
    const int w    = s_w;
    if (lstm < 0) return;

    const float* W_ih = lstm ? W_ih2 : W_ih1;
    const float* W_hh = lstm ? W_hh2 : W_hh1;
    const float* b_ih = lstm ? b_ih2 : b_ih1;
    const float* b_hh = lstm ? b_hh2 : b_hh1;
    const float* W_a  = lstm ? W_zeta : W_xyz;
    const float* W_b  = lstm ? W_pqr  : W_uvw;

    ull* hb = hrot + (size_t)lstm * D_SLOTS * 512;

    __shared__ __align__(16) float h_lds[2][528];   // [4 cb][132] padded
    __shared__ float sa_lds[2][20];
    __shared__ float wih_lds[64 * 19];
    __shared__ float pj_lds[6 * 512];

    // lane decomposition: row r = lane>>2 (16 rows/wave), col-block cb = lane&3
    const int r  = lane >> 2;
    const int cb = lane & 3;
    const int gt = r >> 2;        // gate 0..3 (i,f,g,o)
    const int jj = r & 3;         // j within wave's 4
    const int G  = gt * 512 + (w << 4) + (wv << 2) + jj;   // global gate row

    // W_hh slice: 128 weights / thread in AGPRs (R8/R10-proven resident)
    float wa[128];
    {
        const float4* wp4 = (const float4*)(W_hh + (size_t)G * 512 + cb * 128);
        #pragma unroll
        for (int k = 0; k < 32; ++k) {
            float4 t4 = wp4[k];
            asm volatile("v_accvgpr_write_b32 %0, %1" : "=a"(wa[4 * k + 0]) : "v"(t4.x));
            asm volatile("v_accvgpr_write_b32 %0, %1" : "=a"(wa[4 * k + 1]) : "v"(t4.y));
            asm volatile("v_accvgpr_write_b32 %0, %1" : "=a"(wa[4 * k + 2]) : "v"(t4.z));
            asm volatile("v_accvgpr_write_b32 %0, %1" : "=a"(wa[4 * k + 3]) : "v"(t4.w));
        }
    }
    // W_ih rows (layout: [wv*16 + r][19])
    for (int idx = tid; idx < 64 * 19; idx += THREADS) {
        int rr = idx / 19, kk = idx - rr * 19;
        int v2 = rr >> 4, r2 = rr & 15;
        int G2 = (r2 >> 2) * 512 + (w << 4) + (v2 << 2) + (r2 & 3);
        wih_lds[idx] = W_ih[G2 * 19 + kk];
    }
    // full projection weights (every WG can project the whole h)
    for (int idx = tid; idx < 6 * 512; idx += THREADS) {
        int o = idx >> 9, c = idx & 511;
        pj_lds[idx] = (o < 3) ? W_a[o * 512 + c] : W_b[(o - 3) * 512 + c];
    }
    const float bsum = b_ih[G] + b_hh[G];

    // AGPR ballast: force regs/wave > 256 -> 1 wave/SIMD -> CU-exclusive WG
    float ball[16];
    #pragma unroll
    for (int k = 0; k < 16; ++k)
        asm volatile("v_accvgpr_write_b32 %0, %1" : "=a"(ball[k]) : "v"(bsum));

    // projection biases (wave 1)
    float pb[6] = {0.f, 0.f, 0.f, 0.f, 0.f, 0.f};
    if (wv == 1) {
        const float* ba = lstm ? b_zeta : b_xyz;
        const float* bb = lstm ? b_pqr  : b_uvw;
        #pragma unroll
        for (int o = 0; o < 3; ++o) { pb[o] = ba[o]; pb[o + 3] = bb[o]; }
    }

    float c_reg = 0.0f;
    int   thr   = 64;
    __syncthreads();

    for (int t = 0; t <= T_STEPS; ++t) {
        const int b = t & 1;

        // issue sa[t] load early (completes under the poll's vmcnt)
        float sval = 0.f;
        const bool do_sa = (wv == 3 && lane < 19 && t < T_STEPS);
        if (do_sa) sval = sa[(size_t)t * 19 + lane];

        // ---- 1. poll-and-gather h_{t-1} into h_lds[b] (padded) ----
        {
            const int j    = 2 * tid;
            const int pidx = ((j >> 7) * 132) + (j & 127);
            if (t > 0) {
                ull* sp = hb + (size_t)((uint32)(t - 1) & (D_SLOTS - 1)) * 512 + j;
                const uint32 tag = (uint32)t;
                u32x4 pv;
                int spin = 0;
                for (;;) {
                    poll16(sp, pv);
                    if (pv.x == tag && pv.z == tag) break;
                    if (++spin >= thr) {
                        ull a = rescue_rmw(sp);
                        ull bq = rescue_rmw(sp + 1);
                        if ((uint32)a == tag && (uint32)bq == tag) {
                            pv.x = (uint32)a; pv.y = (uint32)(a >> 32);
                            pv.z = (uint32)bq; pv.w = (uint32)(bq >> 32);
                            break;
                        }
                        thr = 2;
                        spin = 0;
                    }
                }
                h_lds[b][pidx]     = __uint_as_float(pv.y);
                h_lds[b][pidx + 1] = __uint_as_float(pv.w);
            } else {
                h_lds[b][pidx] = 0.f;
                h_lds[b][pidx + 1] = 0.f;
            }
        }
        if (do_sa) sa_lds[b][lane] = sval;
        __syncthreads();

        // ---- 2. exact projection of h_{t-1} -> out[t-1] (rotating WG, wave 1) ----
        if (t > 0 && wv == 1 && (((t - 1) & 31) == w)) {
            float a0 = 0.f, a1 = 0.f, a2 = 0.f, a3 = 0.f, a4 = 0.f, a5 = 0.f;
            #pragma unroll
            for (int m = 0; m < 8; ++m) {
                int c = lane + (m << 6);
                float hv = h_lds[b][((c >> 7) * 132) + (c & 127)];
                a0 = fmaf(hv, pj_lds[c],        a0);
                a1 = fmaf(hv, pj_lds[512 + c],  a1);
                a2 = fmaf(hv, pj_lds[1024 + c], a2);
                a3 = fmaf(hv, pj_lds[1536 + c], a3);
                a4 = fmaf(hv, pj_lds[2048 + c], a4);
                a5 = fmaf(hv, pj_lds[2560 + c], a5);
            }
            a0 = wred64(a0); a1 = wred64(a1); a2 = wred64(a2);
            a3 = wred64(a3); a4 = wred64(a4); a5 = wred64(a5);
            if (lane == 0) {
                size_t ob = (size_t)(t - 1) * 12;
                int ca = 3 * lstm, cbb = 6 + 3 * lstm;
                out[ob + ca + 0]  = a0 + pb[0];
                out[ob + ca + 1]  = a1 + pb[1];
                out[ob + ca + 2]  = a2 + pb[2];
                out[ob + cbb + 0] = a3 + pb[3];
                out[ob + cbb + 1] = a4 + pb[4];
                out[ob + cbb + 2] = a5 + pb[5];
            }
        }
        if (t == T_STEPS) break;

        // ---- 3. mat-vec: row r, cols [cb*128, cb*128+128) + gx slice ----
        float part = (cb == 0) ? bsum : 0.f;
        {
            const int base = (wv * 16 + r) * 19;
            const int k0 = cb * 5;
            #pragma unroll
            for (int i = 0; i < 5; ++i) {
                int k = k0 + i;
                if (k < 19) part = fmaf(sa_lds[b][k], wih_lds[base + k], part);
            }
        }
        {
            const float4* hp4 = (const float4*)(&h_lds[b][cb * 132]);
            float ax = 0.f, ay = 0.f, az = 0.f, aw2 = 0.f;
            #pragma unroll
            for (int k = 0; k < 32; ++k) {
                float4 hv = hp4[k];
                float w0, w1, w2, w3;
                asm volatile("v_accvgpr_read_b32 %0, %1" : "=v"(w0) : "a"(wa[4 * k + 0]));
                asm volatile("v_accvgpr_read_b32 %0, %1" : "=v"(w1) : "a"(wa[4 * k + 1]));
                asm volatile("v_accvgpr_read_b32 %0, %1" : "=v"(w2) : "a"(wa[4 * k + 2]));
                asm volatile("v_accvgpr_read_b32 %0, %1" : "=v"(w3) : "a"(wa[4 * k + 3]));
                ax  = fmaf(w0, hv.x, ax);
                ay  = fmaf(w1, hv.y, ay);
                az  = fmaf(w2, hv.z, az);
                aw2 = fmaf(w3, hv.w, aw2);
            }
            part += (ax + ay) + (az + aw2);
        }
        // reduce across the 4 col-blocks (lanes 4r..4r+3)
        part += __shfl_xor(part, 1);
        part += __shfl_xor(part, 2);

        // ---- 4. gates + cell update + publish (all within the wave) ----
        float act = (gt == 2) ? ftanh(part) : fsig(part);
        float i_v = __shfl(act, 4 * jj);
        float f_v = __shfl(act, 16 + 4 * jj);
        float g_v = __shfl(act, 32 + 4 * jj);
        float o_v = __shfl(act, 48 + 4 * jj);

        if (r < 4 && cb == 0) {      // lanes 0,4,8,12: j = jj = r
            c_reg = f_v * c_reg + i_v * g_v;
            float hn = o_v * ftanh(c_reg);
            ull pk = ((ull)__float_as_uint(hn) << 32) | (ull)(uint32)(t + 1);
            __hip_atomic_store(
                &hb[(size_t)((uint32)t & (D_SLOTS - 1)) * 512 + (w << 4) + (wv << 2) + r],
                pk, __ATOMIC_RELAXED, __HIP_MEMORY_SCOPE_WORKGROUP);
        }
    }

    // keep ballast AGPRs live (branch never taken; compiler can't prove it)
    if (lstm < -1) {
        float s = 0.f;
        #pragma unroll
        for (int k = 0; k < 16; ++k) {
            float tv;
            asm volatile("v_accvgpr_read_b32 %0, %1" : "=v"(tv) : "a"(ball[k]));
            s += tv;
        }
        ((float*)claim)[31] = s;
    }
}

extern "C" void kernel_launch(void* const* d_in, const int* in_sizes, int n_in,
                              void* d_out, int out_size, void* d_ws, size_t ws_size,
                              hipStream_t stream)
{
    const float* sa    = (const float*)d_in[0];
    const float* W_ih1 = (const float*)d_in[1];
    const float* W_hh1 = (const float*)d_in[2];
    const float* b_ih1 = (const float*)d_in[3];
    const float* b_hh1 = (const float*)d_in[4];
    const float* W_ih2 = (const float*)d_in[5];
    const float* W_hh2 = (const float*)d_in[6];
    const float* b_ih2 = (const float*)d_in[7];
    const float* b_hh2 = (const float*)d_in[8];
    const float* W_xyz = (const float*)d_in[9];
    const float* b_xyz = (const float*)d_in[10];
    const float* W_zeta= (const float*)d_in[11];
    const float* b_zeta= (const float*)d_in[12];
    const float* W_uvw = (const float*)d_in[13];
    const float* b_uvw = (const float*)d_in[14];
    const float* W_pqr = (const float*)d_in[15];
    const float* b_pqr = (const float*)d_in[16];

    float*  out   = (float*)d_out;
    ull*    hrot  = (ull*)d_ws;
    uint32* claim = (uint32*)((char*)d_ws + 2 * D_SLOTS * 512 * sizeof(ull));

    // zero hrot tags + claim area every call (graph-replayed)
    hipMemsetAsync(d_ws, 0, 2 * D_SLOTS * 512 * sizeof(ull) + 128, stream);

    lstm_persistent<<<NLAUNCH, THREADS, 0, stream>>>(
        sa, W_ih1, W_hh1, b_ih1, b_hh1, W_ih2, W_hh2, b_ih2, b_hh2,
        W_xyz, b_xyz, W_zeta, b_zeta, W_uvw, b_uvw, W_pqr, b_pqr,
        out, hrot, claim);
}

// Round 13
// 70481.317 us; speedup vs baseline: 6.6051x; 1.1008x over previous
//
#include <hip/hip_runtime.h>

#define T_STEPS 32768
#define THREADS 256
#define NLAUNCH 256   // 1 block per CU; 64 become workers
#define D_SLOTS 4     // h rotation depth

typedef unsigned int uint32;
typedef unsigned long long ull;
typedef unsigned int u32x4 __attribute__((ext_vector_type(4)));

// ws layout:
// [0, 32768)       : hrot = ull[2 lstm][D_SLOTS][512]; each ull = {lo: tag=t+1, hi: f32 h}
// [32768, 32896)   : claim area (32 uints): [0..7] cnt/XCD, [8] rankcnt, [16..23] grank/XCD

__device__ inline float fsig(float x) {
    return __builtin_amdgcn_rcpf(1.f + __expf(-x));
}
__device__ inline float ftanh(float x) {
    return 1.f - 2.f * __builtin_amdgcn_rcpf(1.f + __expf(2.f * x));
}
__device__ inline float wred64(float x) {
    x += __shfl_xor(x, 1);  x += __shfl_xor(x, 2);  x += __shfl_xor(x, 4);
    x += __shfl_xor(x, 8);  x += __shfl_xor(x, 16); x += __shfl_xor(x, 32);
    return x;
}

// Burst poll: 4 parallel nt+sc0 dwordx4 loads (L1 no-allocate -> served by the
// XCD-local L2 the producers write through to; R10-12 proven, zero rescues).
// One L2 round trip covers the lane's full 8-ull slice of h.
__device__ inline void poll4x(const ull* p, u32x4& v0, u32x4& v1, u32x4& v2, u32x4& v3) {
    asm volatile("global_load_dwordx4 %0, %4, off sc0 nt\n\t"
                 "global_load_dwordx4 %1, %4, off offset:1024 sc0 nt\n\t"
                 "global_load_dwordx4 %2, %4, off offset:2048 sc0 nt\n\t"
                 "global_load_dwordx4 %3, %4, off offset:3072 sc0 nt\n\t"
                 "s_waitcnt vmcnt(0)"
                 : "=&v"(v0), "=&v"(v1), "=&v"(v2), "=&v"(v3)
                 : "v"(p) : "memory");
}

__device__ inline uint32 a_add(uint32* p, uint32 v) {
    return __hip_atomic_fetch_add(p, v, __ATOMIC_RELAXED, __HIP_MEMORY_SCOPE_AGENT);
}
__device__ inline uint32 a_ld(const uint32* p) {
    return __hip_atomic_load(p, __ATOMIC_RELAXED, __HIP_MEMORY_SCOPE_AGENT);
}
__device__ inline void a_st(uint32* p, uint32 v) {
    __hip_atomic_store(p, v, __ATOMIC_RELAXED, __HIP_MEMORY_SCOPE_AGENT);
}
__device__ inline ull rescue_rmw(ull* p) {
    return __hip_atomic_fetch_add(p, 0ull, __ATOMIC_RELAXED, __HIP_MEMORY_SCOPE_AGENT);
}

__global__ __launch_bounds__(THREADS, 1)
void lstm_persistent(const float* __restrict__ sa,
                     const float* __restrict__ W_ih1, const float* __restrict__ W_hh1,
                     const float* __restrict__ b_ih1, const float* __restrict__ b_hh1,
                     const float* __restrict__ W_ih2, const float* __restrict__ W_hh2,
                     const float* __restrict__ b_ih2, const float* __restrict__ b_hh2,
                     const float* __restrict__ W_xyz, const float* __restrict__ b_xyz,
                     const float* __restrict__ W_zeta, const float* __restrict__ b_zeta,
                     const float* __restrict__ W_uvw, const float* __restrict__ b_uvw,
                     const float* __restrict__ W_pqr, const float* __restrict__ b_pqr,
                     float* __restrict__ out, ull* hrot, uint32* claim)
{
    const int tid  = threadIdx.x;
    const int wv   = tid >> 6;    // wave 0..3
    const int lane = tid & 63;

    __shared__ int s_lstm, s_w;

    // ---- per-XCD role claiming: one LSTM per XCD (thread 0; R11/12-proven) ----
    if (tid == 0) {
        uint32 xcc;
        asm volatile("s_getreg_b32 %0, hwreg(HW_REG_XCC_ID)" : "=s"(xcc));
        xcc &= 7;
        uint32* cnt     = claim;
        uint32* rankcnt = claim + 8;
        uint32* grank   = claim + 16;

        int lstm = -1, w = 0;
        uint32 slot = a_add(&cnt[xcc], 1);
        if (slot < 32) {
            w = (int)slot;
            if (slot == 31) {
                uint32 rank = a_add(rankcnt, 1);
                a_st(&grank[xcc], (rank < 2) ? (rank + 1) : 0xFEu);
            }
            uint32 g;
            long spins = 0;
            for (;;) {
                g = a_ld(&grank[xcc]);
                if (g != 0) break;
                if (a_ld(rankcnt) >= 2 && ++spins > 200000) { g = 0xFEu; break; }
            }
            if (g != 0xFEu) lstm = (int)g - 1;
        }
        s_lstm = lstm; s_w = w;
    }
    __syncthreads();
    const int lstm = s_lstm;
    const int w    = s_w;
    if (lstm < 0) return;

    const float* W_ih = lstm ? W_ih2 : W_ih1;
    const float* W_hh = lstm ? W_hh2 : W_hh1;
    const float* b_ih = lstm ? b_ih2 : b_ih1;
    const float* b_hh = lstm ? b_hh2 : b_hh1;
    const float* W_a  = lstm ? W_zeta : W_xyz;
    const float* W_b  = lstm ? W_pqr  : W_uvw;

    ull* hb = hrot + (size_t)lstm * D_SLOTS * 512;

    // wave-private h copies (528 = 4*132 padded); shared read-only tables
    __shared__ __align__(16) float hw_all[4][528];
    __shared__ float wih_lds[64 * 19];
    __shared__ float pj_lds[6 * 512];
    float* hw = hw_all[wv];

    // lane decomposition: row r = lane>>2 (16 rows/wave), col-block cb = lane&3
    const int r  = lane >> 2;
    const int cb = lane & 3;
    const int gt = r >> 2;        // gate 0..3 (i,f,g,o)
    const int jj = r & 3;         // j within wave's 4
    const int G  = gt * 512 + (w << 4) + (wv << 2) + jj;   // global gate row

    // W_hh slice: 128 weights / thread in AGPRs (R8+ proven resident)
    float wa[128];
    {
        const float4* wp4 = (const float4*)(W_hh + (size_t)G * 512 + cb * 128);
        #pragma unroll
        for (int k = 0; k < 32; ++k) {
            float4 t4 = wp4[k];
            asm volatile("v_accvgpr_write_b32 %0, %1" : "=a"(wa[4 * k + 0]) : "v"(t4.x));
            asm volatile("v_accvgpr_write_b32 %0, %1" : "=a"(wa[4 * k + 1]) : "v"(t4.y));
            asm volatile("v_accvgpr_write_b32 %0, %1" : "=a"(wa[4 * k + 2]) : "v"(t4.z));
            asm volatile("v_accvgpr_write_b32 %0, %1" : "=a"(wa[4 * k + 3]) : "v"(t4.w));
        }
    }
    // W_ih rows (layout: [wv*16 + r][19])
    for (int idx = tid; idx < 64 * 19; idx += THREADS) {
        int rr = idx / 19, kk = idx - rr * 19;
        int v2 = rr >> 4, r2 = rr & 15;
        int G2 = (r2 >> 2) * 512 + (w << 4) + (v2 << 2) + (r2 & 3);
        wih_lds[idx] = W_ih[G2 * 19 + kk];
    }
    // full projection weights
    for (int idx = tid; idx < 6 * 512; idx += THREADS) {
        int o = idx >> 9, c = idx & 511;
        pj_lds[idx] = (o < 3) ? W_a[o * 512 + c] : W_b[(o - 3) * 512 + c];
    }
    const float bsum = b_ih[G] + b_hh[G];

    // AGPR ballast: keep total regs/wave high -> 1 wave/SIMD
    float ball[16];
    #pragma unroll
    for (int k = 0; k < 16; ++k)
        asm volatile("v_accvgpr_write_b32 %0, %1" : "=a"(ball[k]) : "v"(bsum));

    // projection biases (wave 1)
    float pb[6] = {0.f, 0.f, 0.f, 0.f, 0.f, 0.f};
    if (wv == 1) {
        const float* ba = lstm ? b_zeta : b_xyz;
        const float* bb = lstm ? b_pqr  : b_uvw;
        #pragma unroll
        for (int o = 0; o < 3; ++o) { pb[o] = ba[o]; pb[o + 3] = bb[o]; }
    }

    float c_reg = 0.0f;
    int   thr   = 64;
    __syncthreads();   // tables ready; last barrier -- loop below is barrier-free

    const bool projector = (wv == 1);

    for (int t = 0; t <= T_STEPS; ++t) {
        // final iteration: only the out[T-1] projector wave needs one more gather
        if (t == T_STEPS && !(projector && w == ((T_STEPS - 1) & 31))) break;

        // issue sa[t] early (completes under the poll's vmcnt)
        float sav = 0.f;
        if (lane < 19 && t < T_STEPS) sav = sa[(size_t)t * 19 + lane];

        // ---- 1. wave-autonomous gather of h_{t-1} into hw (no barrier) ----
        if (t > 0) {
            ull* sp = hb + (size_t)((uint32)(t - 1) & (D_SLOTS - 1)) * 512 + 2 * lane;
            const uint32 tag = (uint32)t;
            u32x4 v0, v1, v2, v3;
            int spin = 0;
            for (;;) {
                poll4x(sp, v0, v1, v2, v3);
                if (v0.x == tag && v0.z == tag && v1.x == tag && v1.z == tag &&
                    v2.x == tag && v2.z == tag && v3.x == tag && v3.z == tag) break;
                if (++spin >= thr) {               // memory-side rescue (proven)
                    ull a0 = rescue_rmw(sp),       a1 = rescue_rmw(sp + 1);
                    ull b0 = rescue_rmw(sp + 128), b1 = rescue_rmw(sp + 129);
                    ull c0 = rescue_rmw(sp + 256), c1 = rescue_rmw(sp + 257);
                    ull d0 = rescue_rmw(sp + 384), d1 = rescue_rmw(sp + 385);
                    if ((uint32)a0 == tag && (uint32)a1 == tag &&
                        (uint32)b0 == tag && (uint32)b1 == tag &&
                        (uint32)c0 == tag && (uint32)c1 == tag &&
                        (uint32)d0 == tag && (uint32)d1 == tag) {
                        v0.y = (uint32)(a0 >> 32); v0.w = (uint32)(a1 >> 32);
                        v1.y = (uint32)(b0 >> 32); v1.w = (uint32)(b1 >> 32);
                        v2.y = (uint32)(c0 >> 32); v2.w = (uint32)(c1 >> 32);
                        v3.y = (uint32)(d0 >> 32); v3.w = (uint32)(d1 >> 32);
                        break;
                    }
                    thr = 2;
                    spin = 0;
                }
            }
            // conflict-free scatter: 4 float2 writes, lane stride 8B
            *(float2*)&hw[      2 * lane] = make_float2(__uint_as_float(v0.y), __uint_as_float(v0.w));
            *(float2*)&hw[132 + 2 * lane] = make_float2(__uint_as_float(v1.y), __uint_as_float(v1.w));
            *(float2*)&hw[264 + 2 * lane] = make_float2(__uint_as_float(v2.y), __uint_as_float(v2.w));
            *(float2*)&hw[396 + 2 * lane] = make_float2(__uint_as_float(v3.y), __uint_as_float(v3.w));
        } else if (t == 0) {
            *(float2*)&hw[      2 * lane] = make_float2(0.f, 0.f);
            *(float2*)&hw[132 + 2 * lane] = make_float2(0.f, 0.f);
            *(float2*)&hw[264 + 2 * lane] = make_float2(0.f, 0.f);
            *(float2*)&hw[396 + 2 * lane] = make_float2(0.f, 0.f);
        }
        // (compiler inserts wave-local lgkmcnt before the reads below)

        if (t < T_STEPS) {
            // ---- 2. mat-vec: row r, cols [cb*128, +128) + gx slice ----
            float part = (cb == 0) ? bsum : 0.f;
            {
                const int base = (wv * 16 + r) * 19;
                const int k0 = cb * 5;
                #pragma unroll
                for (int i = 0; i < 5; ++i) {
                    int k = k0 + i;
                    if (k < 19) part = fmaf(__shfl(sav, k), wih_lds[base + k], part);
                }
            }
            {
                const float4* hp4 = (const float4*)&hw[cb * 132];
                float ax = 0.f, ay = 0.f, az = 0.f, aw2 = 0.f;
                #pragma unroll
                for (int k = 0; k < 32; ++k) {
                    float4 hv = hp4[k];
                    float w0, w1, w2, w3;
                    asm volatile("v_accvgpr_read_b32 %0, %1" : "=v"(w0) : "a"(wa[4 * k + 0]));
                    asm volatile("v_accvgpr_read_b32 %0, %1" : "=v"(w1) : "a"(wa[4 * k + 1]));
                    asm volatile("v_accvgpr_read_b32 %0, %1" : "=v"(w2) : "a"(wa[4 * k + 2]));
                    asm volatile("v_accvgpr_read_b32 %0, %1" : "=v"(w3) : "a"(wa[4 * k + 3]));
                    ax  = fmaf(w0, hv.x, ax);
                    ay  = fmaf(w1, hv.y, ay);
                    az  = fmaf(w2, hv.z, az);
                    aw2 = fmaf(w3, hv.w, aw2);
                }
                part += (ax + ay) + (az + aw2);
            }
            part += __shfl_xor(part, 1);
            part += __shfl_xor(part, 2);

            // ---- 3. gates + cell update + publish (wave-local) ----
            float act = (gt == 2) ? ftanh(part) : fsig(part);
            float i_v = __shfl(act, 4 * jj);
            float f_v = __shfl(act, 16 + 4 * jj);
            float g_v = __shfl(act, 32 + 4 * jj);
            float o_v = __shfl(act, 48 + 4 * jj);

            if (r < 4 && cb == 0) {      // lanes 0,4,8,12: j = r
                c_reg = f_v * c_reg + i_v * g_v;
                float hn = o_v * ftanh(c_reg);
                ull pk = ((ull)__float_as_uint(hn) << 32) | (ull)(uint32)(t + 1);
                __hip_atomic_store(
                    &hb[(size_t)((uint32)t & (D_SLOTS - 1)) * 512 + (w << 4) + (wv << 2) + r],
                    pk, __ATOMIC_RELAXED, __HIP_MEMORY_SCOPE_WORKGROUP);
            }
        }

        // ---- 4. exact projection out[t-1] (after publish; off critical path) ----
        if (t > 0 && projector && (((t - 1) & 31) == w)) {
            float a0 = 0.f, a1 = 0.f, a2 = 0.f, a3 = 0.f, a4 = 0.f, a5 = 0.f;
            #pragma unroll
            for (int m = 0; m < 8; ++m) {
                int c = lane + (m << 6);
                float hv = hw[((c >> 7) * 132) + (c & 127)];
                a0 = fmaf(hv, pj_lds[c],        a0);
                a1 = fmaf(hv, pj_lds[512 + c],  a1);
                a2 = fmaf(hv, pj_lds[1024 + c], a2);
                a3 = fmaf(hv, pj_lds[1536 + c], a3);
                a4 = fmaf(hv, pj_lds[2048 + c], a4);
                a5 = fmaf(hv, pj_lds[2560 + c], a5);
            }
            a0 = wred64(a0); a1 = wred64(a1); a2 = wred64(a2);
            a3 = wred64(a3); a4 = wred64(a4); a5 = wred64(a5);
            if (lane == 0) {
                size_t ob = (size_t)(t - 1) * 12;
                int ca = 3 * lstm, cbb = 6 + 3 * lstm;
                out[ob + ca + 0]  = a0 + pb[0];
                out[ob + ca + 1]  = a1 + pb[1];
                out[ob + ca + 2]  = a2 + pb[2];
                out[ob + cbb + 0] = a3 + pb[3];
                out[ob + cbb + 1] = a4 + pb[4];
                out[ob + cbb + 2] = a5 + pb[5];
            }
        }
    }

    // keep ballast AGPRs live (branch never taken; compiler can't prove it)
    if (lstm < -1) {
        float s = 0.f;
        #pragma unroll
        for (int k = 0; k < 16; ++k) {
            float tv;
            asm volatile("v_accvgpr_read_b32 %0, %1" : "=v"(tv) : "a"(ball[k]));
            s += tv;
        }
        ((float*)claim)[31] = s;
    }
}

extern "C" void kernel_launch(void* const* d_in, const int* in_sizes, int n_in,
                              void* d_out, int out_size, void* d_ws, size_t ws_size,
                              hipStream_t stream)
{
    const float* sa    = (const float*)d_in[0];
    const float* W_ih1 = (const float*)d_in[1];
    const float* W_hh1 = (const float*)d_in[2];
    const float* b_ih1 = (const float*)d_in[3];
    const float* b_hh1 = (const float*)d_in[4];
    const float* W_ih2 = (const float*)d_in[5];
    const float* W_hh2 = (const float*)d_in[6];
    const float* b_ih2 = (const float*)d_in[7];
    const float* b_hh2 = (const float*)d_in[8];
    const float* W_xyz = (const float*)d_in[9];
    const float* b_xyz = (const float*)d_in[10];
    const float* W_zeta= (const float*)d_in[11];
    const float* b_zeta= (const float*)d_in[12];
    const float* W_uvw = (const float*)d_in[13];
    const float* b_uvw = (const float*)d_in[14];
    const float* W_pqr = (const float*)d_in[15];
    const float* b_pqr = (const float*)d_in[16];

    float*  out   = (float*)d_out;
    ull*    hrot  = (ull*)d_ws;
    uint32* claim = (uint32*)((char*)d_ws + 2 * D_SLOTS * 512 * sizeof(ull));

    // zero hrot tags + claim area every call (graph-replayed)
    hipMemsetAsync(d_ws, 0, 2 * D_SLOTS * 512 * sizeof(ull) + 128, stream);

    lstm_persistent<<<NLAUNCH, THREADS, 0, stream>>>(
        sa, W_ih1, W_hh1, b_ih1, b_hh1, W_ih2, W_hh2, b_ih2, b_hh2,
        W_xyz, b_xyz, W_zeta, b_zeta, W_uvw, b_uvw, W_pqr, b_pqr,
        out, hrot, claim);
}